// Round 4
// baseline (989.091 us; speedup 1.0000x reference)
//
#include <hip/hip_runtime.h>
#include <stdint.h>

typedef __bf16 bf16_t;
typedef bf16_t bf16x8 __attribute__((ext_vector_type(8)));
typedef float floatx4 __attribute__((ext_vector_type(4)));
typedef ushort ushortx8 __attribute__((ext_vector_type(8)));

__device__ __forceinline__ ushort f2bf(float f) {
  uint u = __float_as_uint(f);
  u += 0x7FFFu + ((u >> 16) & 1u);   // RNE; inputs finite/normal
  return (ushort)(u >> 16);
}
__device__ __forceinline__ float bf2f(ushort h) {
  return __uint_as_float(((uint)h) << 16);
}

// async 16B global->LDS DMA. LDS dest = wave-uniform base + lane*16.
__device__ __forceinline__ void async_cp16(const ushort* g, ushort* l) {
  __builtin_amdgcn_global_load_lds(
      (const __attribute__((address_space(1))) uint32_t*)g,
      (__attribute__((address_space(3))) uint32_t*)l, 16, 0, 0);
}

// ---------------- fp32 -> bf16 convert ----------------
__global__ __launch_bounds__(256) void cvt_f32_bf16(const float* __restrict__ in,
                                                    ushort* __restrict__ out,
                                                    long long n) {
  long long i = (((long long)blockIdx.x) * 256 + threadIdx.x) * 4;
  if (i + 3 < n) {
    float4 f = *(const float4*)(in + i);
    ushort4 o = make_ushort4(f2bf(f.x), f2bf(f.y), f2bf(f.z), f2bf(f.w));
    *(ushort4*)(out + i) = o;
  }
}

// ---- pack Wq/Wk/Wv (fp32) -> Wp[4][1536][512] bf16 (rows: Q,K,V stacked) ----
__global__ __launch_bounds__(256) void pack_w(const float* __restrict__ Wq,
                                              const float* __restrict__ Wk,
                                              const float* __restrict__ Wv,
                                              ushort* __restrict__ Wp) {
  long long t4 = (((long long)blockIdx.x) * 256 + threadIdx.x) * 4;  // < 4*1536*512
  const int k = (int)(t4 & 511);
  const int jr = (int)(t4 >> 9);       // 0..6143
  const int pi = jr / 1536;
  const int j = jr - pi * 1536;
  const int type = j >> 9;             // 0=Q 1=K 2=V
  const int jj = j & 511;
  const float* src = (type == 0 ? Wq : type == 1 ? Wk : Wv) +
                     ((long long)(pi * 512 + jj) << 9) + k;
  float4 f = *(const float4*)src;
  ushort4 o = make_ushort4(f2bf(f.x), f2bf(f.y), f2bf(f.z), f2bf(f.w));
  *(ushort4*)(Wp + t4) = o;
}

__global__ __launch_bounds__(256) void pack_b(const float* __restrict__ bq,
                                              const float* __restrict__ bk,
                                              const float* __restrict__ bv,
                                              float* __restrict__ Bp) {
  const int i = blockIdx.x * 256 + threadIdx.x;  // < 6144
  const int pi = i / 1536;
  const int j = i - pi * 1536;
  const int type = j >> 9;
  const int jj = j & 511;
  Bp[i] = (type == 0 ? bq : type == 1 ? bk : bv)[pi * 512 + jj];
}

// ---------------- BT-form bf16 MFMA GEMM ----------------
// C[m,n] = sum_k A[m,k]*B[n,k]; both operands k-contiguous (lda/ldb strides).
// 128x128 tile, BK=32, DOUBLE-buffered in 32 KiB total LDS (occupancy kept
// at 4 blocks/CU). T3-minimum pipeline with RAW s_barrier + issue-early /
// wait-late vmcnt: per tile {issue 4 DMA for kt+1 | ds_read+16 MFMA on kt |
// s_waitcnt vmcnt(0) | s_barrier}. __syncthreads is NOT used in the loop
// (it drains vmcnt BEFORE the barrier, exposing full staging latency —
// measured rounds 0-3). Race-safety: each wave's ds_reads of buf[cur]
// complete before its MFMAs (compiler lgkm waits); MFMAs precede the
// sched_barrier(0)+vmcnt+s_barrier fence; so after the barrier nobody has
// pending reads/writes on the buffer staged next iteration.
// Bank balance via XOR swizzle folded into the GLOBAL chunk choice:
// LDS[row][c] = G[row][c ^ ((row>>1)&3)] (16B chunks, 4/row); ds_read uses
// col = (quad ^ ((l15>>1)&3))*8 -> even 32-bank spread, 2-way max (free).
// Epilogue: per-wave LDS transpose (stride-68 f32, reuses staging LDS) ->
// 128B/256B coalesced segments instead of 32B/64B scatter.
#define BM 128
#define BN 128
#define BK 32

enum { EP_QKV = 0, EP_SCALE = 2, EP_ACC = 3, EP_FINAL = 4 };

#define SBAR0 __builtin_amdgcn_sched_barrier(0)

template <int MODE, bool ACCUM>
__global__ __launch_bounds__(256, 2)
void gemm_bt(const ushort* __restrict__ Aq, const ushort* __restrict__ Akv,
             const ushort* __restrict__ B,
             void* __restrict__ C, void* __restrict__ C2, void* __restrict__ C3,
             const float* __restrict__ aux,
             int M, int N, int K, int lda, int ldb, int ldc,
             long long sA, long long sB, long long sC, long long sAux,
             float scale) {
  __shared__ __align__(16) ushort sh[2][2][BM * BK];  // [buf][A=0/B=1][...]
  const int b = blockIdx.z;
  const int m0 = blockIdx.y * BM;
  const int n0 = blockIdx.x * BN;
  // EP_QKV: region 0 = Q (A=qs), 1 = K, 2 = V (A=kvs). Block-uniform.
  const int reg = (MODE == EP_QKV) ? (n0 >> 9) : 0;
  const ushort* Ab = ((MODE == EP_QKV && reg > 0) ? Akv : Aq) + (long long)b * sA;
  const ushort* Bb = B + (long long)b * sB;
  const int t = threadIdx.x;
  const int lane = t & 63;
  const int w = t >> 6;
  const int wr = (w >> 1) * 64;
  const int wc = (w & 1) * 64;
  const int l15 = lane & 15;
  const int quad = lane >> 4;

  floatx4 acc[4][4];
#pragma unroll
  for (int i = 0; i < 4; i++)
#pragma unroll
    for (int j = 0; j < 4; j++)
#pragma unroll
      for (int r = 0; r < 4; r++) acc[i][j][r] = 0.f;

  // staging: 512 chunks of 8 bf16 per 128x32 operand tile; wave w covers
  // chunks [w*128, w*128+128) via 2 lds-DMA instructions per operand.
  long long offA[2], offB[2];
  int loff[2];
#pragma unroll
  for (int i = 0; i < 2; i++) {
    const int q = w * 128 + i * 64 + lane;
    const int row = q >> 2;                       // row in tile (0..127)
    const int c = q & 3;                          // LDS chunk within row
    const int gk = (c ^ ((row >> 1) & 3)) * 8;    // swizzled global chunk
    offA[i] = (long long)(m0 + row) * lda + gk;
    offB[i] = (long long)(n0 + row) * ldb + gk;
    loff[i] = (w * 128 + i * 64) * 8;  // wave-uniform LDS base (HW adds lane*16)
  }

  const int col = ((quad ^ ((l15 >> 1) & 3)) << 3);  // swizzled read col (ushorts)
  const int nt = K >> 5;

  // prologue: tile 0 -> buf 0
#pragma unroll
  for (int i = 0; i < 2; i++) async_cp16(Ab + offA[i], &sh[0][0][loff[i]]);
#pragma unroll
  for (int i = 0; i < 2; i++) async_cp16(Bb + offB[i], &sh[0][1][loff[i]]);
  asm volatile("s_waitcnt vmcnt(0)" ::: "memory");
  SBAR0;
  __builtin_amdgcn_s_barrier();
  SBAR0;

  for (int kt = 0; kt < nt; ++kt) {
    const int cur = kt & 1;
    // issue next tile's staging; it flies under this tile's reads + MFMA
    if (kt + 1 < nt) {
      const int k1 = (kt + 1) << 5;
#pragma unroll
      for (int i = 0; i < 2; i++)
        async_cp16(Ab + offA[i] + k1, &sh[cur ^ 1][0][loff[i]]);
#pragma unroll
      for (int i = 0; i < 2; i++)
        async_cp16(Bb + offB[i] + k1, &sh[cur ^ 1][1][loff[i]]);
    }
    const ushort* Asb = sh[cur][0];
    const ushort* Bsb = sh[cur][1];
    bf16x8 af[4], bfr[4];
#pragma unroll
    for (int mi = 0; mi < 4; mi++)
      af[mi] = *(const bf16x8*)(Asb + (wr + mi * 16 + l15) * BK + col);
#pragma unroll
    for (int ni = 0; ni < 4; ni++)
      bfr[ni] = *(const bf16x8*)(Bsb + (wc + ni * 16 + l15) * BK + col);
#pragma unroll
    for (int mi = 0; mi < 4; mi++)
#pragma unroll
      for (int ni = 0; ni < 4; ni++)
        acc[mi][ni] = __builtin_amdgcn_mfma_f32_16x16x32_bf16(
            af[mi], bfr[ni], acc[mi][ni], 0, 0, 0);
    // wait-late: DMAs had the whole compute phase in flight
    SBAR0;
    asm volatile("s_waitcnt vmcnt(0)" ::: "memory");
    SBAR0;
    __builtin_amdgcn_s_barrier();
    SBAR0;
  }

  // ---------------- epilogue ----------------
  // Per-column bias (QKV only); col for lane = n0+wc+ni*16+l15.
  float biasv[4];
  if (MODE == EP_QKV) {
#pragma unroll
    for (int ni = 0; ni < 4; ni++) biasv[ni] = aux[n0 + wc + ni * 16 + l15];
  }

  if (MODE == EP_QKV && reg == 2) {
    // V region: write transposed Vt[b2][vcol][token] (token = gm, ushort4 runs)
#pragma unroll
    for (int mi = 0; mi < 4; mi++) {
#pragma unroll
      for (int ni = 0; ni < 4; ni++) {
        const int gm0 = m0 + wr + mi * 16 + quad * 4;
        const int gn = n0 + wc + ni * 16 + l15;
        const float bias = biasv[ni];
        const int b2 = gm0 >> 11;
        const int gmL = gm0 & 2047;
        ushort4 o;
        o.x = f2bf(acc[mi][ni][0] + bias);
        o.y = f2bf(acc[mi][ni][1] + bias);
        o.z = f2bf(acc[mi][ni][2] + bias);
        o.w = f2bf(acc[mi][ni][3] + bias);
        *(ushort4*)((ushort*)C2 + (long long)b2 * (512 * 2048) +
                    (long long)(gn - 1024) * 2048 + gmL) = o;
      }
    }
    return;
  }

  // Transposing epilogue: per wave a 16x64 f32 tile (stride 68, 4352B) in the
  // staging LDS (4 waves * 4352 = 17408B <= 32768B). 4 passes (one per mi).
  // Each wave uses only its own region; loop's final s_barrier freed the LDS.
  __syncthreads();
  float* shf = (float*)&sh[0][0][0];
  const int wbase = w * 1088;  // floats

#pragma unroll
  for (int mi = 0; mi < 4; mi++) {
    // -- write phase: 16 scalar ds_writes (2-way bank alias max: free)
#pragma unroll
    for (int ni = 0; ni < 4; ni++) {
#pragma unroll
      for (int r = 0; r < 4; r++) {
        float v = acc[mi][ni][r];
        if (MODE == EP_QKV) v += biasv[ni];
        if (MODE == EP_SCALE) v *= scale;
        shf[wbase + (quad * 4 + r) * 68 + ni * 16 + l15] = v;
      }
    }
    asm volatile("s_waitcnt lgkmcnt(0)" ::: "memory");
    __builtin_amdgcn_sched_barrier(0);

    const int gmb = m0 + wr + mi * 16;
    if (MODE == EP_FINAL) {
      // fp32 out: 4 sub-iters of (4 rows x 16 lanes x float4) = 256B segments
#pragma unroll
      for (int j = 0; j < 4; j++) {
        const int rr = j * 4 + (lane >> 4);
        const int c0 = (lane & 15) * 4;
        float4 f = *(const float4*)&shf[wbase + rr * 68 + c0];
        const int gm = gmb + rr;
        const int gn = n0 + wc + c0;
        float4 x = *(const float4*)(aux + (long long)b * sAux +
                                    (long long)gm * N + gn);
        f.x += x.x; f.y += x.y; f.z += x.z; f.w += x.w;
        *(float4*)((float*)C + (long long)b * sC + (long long)gm * ldc + gn) = f;
      }
    } else {
      // bf16 out: 2 sub-iters of (8 rows x 8 lanes x ushort8) = 128B segments
#pragma unroll
      for (int j = 0; j < 2; j++) {
        const int rr = j * 8 + (lane >> 3);
        const int c0 = (lane & 7) * 8;
        float4 f0 = *(const float4*)&shf[wbase + rr * 68 + c0];
        float4 f1 = *(const float4*)&shf[wbase + rr * 68 + c0 + 4];
        const int gm = gmb + rr;
        const int gn = n0 + wc + c0;
        float vv[8] = {f0.x, f0.y, f0.z, f0.w, f1.x, f1.y, f1.z, f1.w};
        ushort* base;
        long long off;
        if (MODE == EP_QKV) {
          if (reg == 0) { base = (ushort*)C;  off = (long long)gm * ldc + gn; }
          else          { base = (ushort*)C3; off = (long long)gm * ldc + (gn - 512); }
        } else {
          base = (ushort*)C;
          off = (long long)b * sC + (long long)gm * ldc + gn;
        }
        if (MODE == EP_ACC && ACCUM) {
          ushortx8 old = *(const ushortx8*)(base + off);
#pragma unroll
          for (int e = 0; e < 8; e++) vv[e] += bf2f(old[e]);
        }
        ushortx8 o;
#pragma unroll
        for (int e = 0; e < 8; e++) o[e] = f2bf(vv[e]);
        *(ushortx8*)(base + off) = o;
      }
    }
  }
}

// ---------------- row softmax over 2048 bf16, in place ----------------
__global__ __launch_bounds__(256) void softmax_rows(ushort* __restrict__ S) {
  const long long row = blockIdx.x;
  ushort* p = S + (row << 11);
  const int t = threadIdx.x;
  const int lane = t & 63;
  const int w = t >> 6;

  uint4 raw = *(const uint4*)(p + (t << 3));
  const ushort* rs = (const ushort*)&raw;
  float v[8];
  for (int i = 0; i < 8; i++) v[i] = bf2f(rs[i]);

  float mx = v[0];
  for (int i = 1; i < 8; i++) mx = fmaxf(mx, v[i]);
  for (int off = 32; off; off >>= 1) mx = fmaxf(mx, __shfl_xor(mx, off, 64));
  __shared__ float redm[4];
  __shared__ float reds[4];
  if (lane == 0) redm[w] = mx;
  __syncthreads();
  mx = fmaxf(fmaxf(redm[0], redm[1]), fmaxf(redm[2], redm[3]));

  float s = 0.f;
  for (int i = 0; i < 8; i++) {
    v[i] = __expf(v[i] - mx);
    s += v[i];
  }
  for (int off = 32; off; off >>= 1) s += __shfl_xor(s, off, 64);
  if (lane == 0) reds[w] = s;
  __syncthreads();
  s = (reds[0] + reds[1]) + (reds[2] + reds[3]);
  const float inv = 1.0f / s;

  ushort o[8];
  for (int i = 0; i < 8; i++) o[i] = f2bf(v[i] * inv);
  *(uint4*)(p + (t << 3)) = *(const uint4*)o;
}

// ---------------- orchestration ----------------
extern "C" void kernel_launch(void* const* d_in, const int* in_sizes, int n_in,
                              void* d_out, int out_size, void* d_ws, size_t ws_size,
                              hipStream_t stream) {
  const float* Itime = (const float*)d_in[0];
  const float* Ispace = (const float*)d_in[1];
  const float* x0 = (const float*)d_in[2];
  const float* Wq = (const float*)d_in[3];
  const float* bq = (const float*)d_in[4];
  const float* Wk = (const float*)d_in[5];
  const float* bk = (const float*)d_in[6];
  const float* Wv = (const float*)d_in[7];
  const float* bv = (const float*)d_in[8];
  float* out = (float*)d_out;

  const long long SZX = 8388608;        // 8*2048*512
  const long long SZWP = 4LL * 1536 * 512;
  const long long SZS = 33554432;       // 8*2048*2048

  ushort* p = (ushort*)d_ws;
  ushort* Tb = p;   p += SZX;    // Itime bf16
  ushort* Sb = p;   p += SZX;    // Ispace bf16
  ushort* Wp = p;   p += SZWP;   // packed [4][1536][512] (Q,K,V rows)
  ushort* Qb = p;   p += SZX;    // Q proj [16384][512]
  ushort* Kb = p;   p += SZX;    // K proj [16384][512]
  ushort* Vt = p;   p += SZX;    // V^T [8][512][2048]
  ushort* Abf = p;  p += SZX;    // FTT + FTS
  ushort* Cbf = p;  p += SZX;    // FSS + FST
  ushort* Sc = p;   p += SZS;    // scores / probs (bf16)
  float* Bp = (float*)p;         // packed biases [4][1536] fp32 (24 KB)
  // total ws use ≈ 190.9 MB

  const dim3 blk(256);
  cvt_f32_bf16<<<dim3(8192), blk, 0, stream>>>(Itime, Tb, SZX);
  cvt_f32_bf16<<<dim3(8192), blk, 0, stream>>>(Ispace, Sb, SZX);
  pack_w<<<dim3(3072), blk, 0, stream>>>(Wq, Wk, Wv, Wp);
  pack_b<<<dim3(24), blk, 0, stream>>>(bq, bk, bv, Bp);

  const float scale = 0.04419417382415922f;  // 1/sqrt(512)

  auto attn = [&](const ushort* qs, const ushort* kvs, int pi,
                  ushort* dest, bool accum) {
    const ushort* Wqi = Wp + (long long)pi * 1536 * 512;
    const float* Bqi = Bp + pi * 1536;
    // Fused Q+K+V projection: [16384,1536]; region (Q/K/V) block-uniform.
    // Q -> Qb, K -> Kb, V -> Vt (transposed per batch).
    gemm_bt<EP_QKV, false><<<dim3(12, 128, 1), blk, 0, stream>>>(
        qs, kvs, Wqi, Qb, Vt, Kb, Bqi, 16384, 1536, 512, 512, 512, 512,
        0, 0, 0, 0, 0.f);
    // scores: S = scale * Q K^T (per batch 2048x2048)
    gemm_bt<EP_SCALE, false><<<dim3(16, 16, 8), blk, 0, stream>>>(
        Qb, Qb, Kb, Sc, nullptr, nullptr, nullptr, 2048, 2048, 512, 512, 512,
        2048, 1048576, 1048576, 4194304, 0, scale);
    softmax_rows<<<dim3(16384), blk, 0, stream>>>(Sc);
    // O (+)= P V : per batch M=2048, N=512, K=2048; B operand = Vt rows
    if (accum)
      gemm_bt<EP_ACC, true><<<dim3(4, 16, 8), blk, 0, stream>>>(
          Sc, Sc, Vt, dest, nullptr, nullptr, nullptr, 2048, 512, 2048, 2048,
          2048, 512, 4194304, 1048576, 1048576, 0, 0.f);
    else
      gemm_bt<EP_ACC, false><<<dim3(4, 16, 8), blk, 0, stream>>>(
          Sc, Sc, Vt, dest, nullptr, nullptr, nullptr, 2048, 512, 2048, 2048,
          2048, 512, 4194304, 1048576, 1048576, 0, 0.f);
  };

  attn(Tb, Tb, 0, Abf, false);   // FTT
  attn(Tb, Sb, 2, Abf, true);    // + FTS
  attn(Sb, Sb, 1, Cbf, false);   // FSS
  attn(Sb, Tb, 3, Cbf, true);    // + FST

  // out = Abf . Cbf^T + x_origin (fp32)
  gemm_bt<EP_FINAL, false><<<dim3(16, 16, 8), blk, 0, stream>>>(
      Abf, Abf, Cbf, out, nullptr, nullptr, x0, 2048, 2048, 512, 512, 512,
      2048, 1048576, 1048576, 4194304, 4194304, 0.f);
}

// Round 5
// 805.161 us; speedup vs baseline: 1.2284x; 1.2284x over previous
//
#include <hip/hip_runtime.h>
#include <stdint.h>

typedef __bf16 bf16_t;
typedef bf16_t bf16x8 __attribute__((ext_vector_type(8)));
typedef float floatx4 __attribute__((ext_vector_type(4)));
typedef ushort ushortx8 __attribute__((ext_vector_type(8)));

__device__ __forceinline__ ushort f2bf(float f) {
  uint u = __float_as_uint(f);
  u += 0x7FFFu + ((u >> 16) & 1u);   // RNE; inputs finite/normal
  return (ushort)(u >> 16);
}
__device__ __forceinline__ float bf2f(ushort h) {
  return __uint_as_float(((uint)h) << 16);
}

// async 16B global->LDS DMA. LDS dest = wave-uniform base + lane*16.
__device__ __forceinline__ void async_cp16(const ushort* g, ushort* l) {
  __builtin_amdgcn_global_load_lds(
      (const __attribute__((address_space(1))) uint32_t*)g,
      (__attribute__((address_space(3))) uint32_t*)l, 16, 0, 0);
}

// ---------------- fp32 -> bf16 convert ----------------
__global__ __launch_bounds__(256) void cvt_f32_bf16(const float* __restrict__ in,
                                                    ushort* __restrict__ out,
                                                    long long n) {
  long long i = (((long long)blockIdx.x) * 256 + threadIdx.x) * 4;
  if (i + 3 < n) {
    float4 f = *(const float4*)(in + i);
    ushort4 o = make_ushort4(f2bf(f.x), f2bf(f.y), f2bf(f.z), f2bf(f.w));
    *(ushort4*)(out + i) = o;
  }
}

// ---- pack Wq/Wk/Wv (fp32) -> Wp[4][1536][512] bf16 (rows: Q,K,V stacked) ----
__global__ __launch_bounds__(256) void pack_w(const float* __restrict__ Wq,
                                              const float* __restrict__ Wk,
                                              const float* __restrict__ Wv,
                                              ushort* __restrict__ Wp) {
  long long t4 = (((long long)blockIdx.x) * 256 + threadIdx.x) * 4;  // < 4*1536*512
  const int k = (int)(t4 & 511);
  const int jr = (int)(t4 >> 9);       // 0..6143
  const int pi = jr / 1536;
  const int j = jr - pi * 1536;
  const int type = j >> 9;             // 0=Q 1=K 2=V
  const int jj = j & 511;
  const float* src = (type == 0 ? Wq : type == 1 ? Wk : Wv) +
                     ((long long)(pi * 512 + jj) << 9) + k;
  float4 f = *(const float4*)src;
  ushort4 o = make_ushort4(f2bf(f.x), f2bf(f.y), f2bf(f.z), f2bf(f.w));
  *(ushort4*)(Wp + t4) = o;
}

__global__ __launch_bounds__(256) void pack_b(const float* __restrict__ bq,
                                              const float* __restrict__ bk,
                                              const float* __restrict__ bv,
                                              float* __restrict__ Bp) {
  const int i = blockIdx.x * 256 + threadIdx.x;  // < 6144
  const int pi = i / 1536;
  const int j = i - pi * 1536;
  const int type = j >> 9;
  const int jj = j & 511;
  Bp[i] = (type == 0 ? bq : type == 1 ? bk : bv)[pi * 512 + jj];
}

// ---------------- BT-form bf16 MFMA GEMM ----------------
// C[m,n] = sum_k A[m,k]*B[n,k]; both operands k-contiguous (lda/ldb strides).
// BK=64, 128x128 tile, single-buffered 32 KiB LDS (proven engine; every
// K-loop restructure attempt — 256^2 8-phase, BK=64 dbuf, BK=32 dbuf+raw
// barriers — regressed across rounds 1/2/4). Bank balance via XOR swizzle
// folded into the GLOBAL chunk choice: LDS[row][c] = G[row][c^(row&7)].
// T1 XCD-aware chunked block swizzle: all grids have total%8==0; chunk
// q=T/8 puts one contiguous run per XCD. For scores/PV/final, q equals one
// batch's blocks -> per-XCD L2 working set (B panels) = 1.5-2 MB, fits the
// 4 MiB per-XCD L2. QKV: full W (1.5 MB) per XCD.
// Epilogue: per-wave LDS transpose (stride-68 f32, reuses staging LDS) ->
// 128B/256B coalesced segments instead of 32B/64B scatter.
#define BM 128
#define BN 128
#define BK 64

enum { EP_QKV = 0, EP_SCALE = 2, EP_ACC = 3, EP_FINAL = 4 };

template <int MODE, bool ACCUM>
__global__ __launch_bounds__(256, 2)
void gemm_bt(const ushort* __restrict__ Aq, const ushort* __restrict__ Akv,
             const ushort* __restrict__ B,
             void* __restrict__ C, void* __restrict__ C2, void* __restrict__ C3,
             const float* __restrict__ aux,
             int M, int N, int K, int lda, int ldb, int ldc,
             long long sA, long long sB, long long sC, long long sAux,
             float scale) {
  __shared__ __align__(16) ushort sh[2][BM * BK];  // As=sh[0], Bs=sh[1]

  // XCD-aware chunked swizzle (bijective: T%8==0 at every call site).
  int bx = blockIdx.x, by = blockIdx.y, bz = blockIdx.z;
  {
    const int gx = gridDim.x, gy = gridDim.y;
    const int T = gx * gy * (int)gridDim.z;
    int f = bx + gx * (by + gy * bz);
    const int q = T >> 3;
    f = (f & 7) * q + (f >> 3);
    bx = f % gx;
    const int r2 = f / gx;
    by = r2 % gy;
    bz = r2 / gy;
  }
  const int b = bz;
  const int m0 = by * BM;
  const int n0 = bx * BN;
  // EP_QKV: region 0 = Q (A=qs), 1 = K, 2 = V (A=kvs). Block-uniform.
  const int reg = (MODE == EP_QKV) ? (n0 >> 9) : 0;
  const ushort* Ab = ((MODE == EP_QKV && reg > 0) ? Akv : Aq) + (long long)b * sA;
  const ushort* Bb = B + (long long)b * sB;
  const int t = threadIdx.x;
  const int lane = t & 63;
  const int w = t >> 6;
  const int wr = (w >> 1) * 64;
  const int wc = (w & 1) * 64;
  const int l15 = lane & 15;
  const int quad = lane >> 4;

  floatx4 acc[4][4];
#pragma unroll
  for (int i = 0; i < 4; i++)
#pragma unroll
    for (int j = 0; j < 4; j++)
#pragma unroll
      for (int r = 0; r < 4; r++) acc[i][j][r] = 0.f;

  // staging: 1024 chunks of 8 bf16 per 128x64 tile; wave w covers chunks
  // [w*256, w*256+256) via 4 lds-DMA instructions per operand.
  long long offA[4], offB[4];
  int loff[4];
#pragma unroll
  for (int i = 0; i < 4; i++) {
    const int q = w * 256 + i * 64 + lane;
    const int row = q >> 3;
    const int gk = ((q & 7) ^ (row & 7)) * 8;
    offA[i] = (long long)(m0 + row) * lda + gk;
    offB[i] = (long long)(n0 + row) * ldb + gk;
    loff[i] = (w * 256 + i * 64) * 8;  // wave-uniform LDS base (HW adds lane*16)
  }

  const int x7 = l15 & 7;
  for (int k0 = 0; k0 < K; k0 += BK) {
    __syncthreads();  // prev iter's ds_reads done before overwrite
#pragma unroll
    for (int i = 0; i < 4; i++) async_cp16(Ab + offA[i] + k0, &sh[0][loff[i]]);
#pragma unroll
    for (int i = 0; i < 4; i++) async_cp16(Bb + offB[i] + k0, &sh[1][loff[i]]);
    __syncthreads();  // drains vmcnt -> staging visible

#pragma unroll
    for (int s = 0; s < 2; s++) {
      const int col = ((s * 4 + quad) ^ x7) * 8;
      bf16x8 af[4], bfr[4];
#pragma unroll
      for (int mi = 0; mi < 4; mi++)
        af[mi] = *(const bf16x8*)(&sh[0][0] + (wr + mi * 16 + l15) * BK + col);
#pragma unroll
      for (int ni = 0; ni < 4; ni++)
        bfr[ni] = *(const bf16x8*)(&sh[1][0] + (wc + ni * 16 + l15) * BK + col);
#pragma unroll
      for (int mi = 0; mi < 4; mi++)
#pragma unroll
        for (int ni = 0; ni < 4; ni++)
          acc[mi][ni] = __builtin_amdgcn_mfma_f32_16x16x32_bf16(
              af[mi], bfr[ni], acc[mi][ni], 0, 0, 0);
    }
  }

  // ---------------- epilogue ----------------
  // Per-column bias (QKV only); col for lane = n0+wc+ni*16+l15.
  float biasv[4];
  if (MODE == EP_QKV) {
#pragma unroll
    for (int ni = 0; ni < 4; ni++) biasv[ni] = aux[n0 + wc + ni * 16 + l15];
  }

  if (MODE == EP_QKV && reg == 2) {
    // V region: write transposed Vt[b2][vcol][token] (token = gm, ushort4 runs)
#pragma unroll
    for (int mi = 0; mi < 4; mi++) {
#pragma unroll
      for (int ni = 0; ni < 4; ni++) {
        const int gm0 = m0 + wr + mi * 16 + quad * 4;
        const int gn = n0 + wc + ni * 16 + l15;
        const float bias = biasv[ni];
        const int b2 = gm0 >> 11;
        const int gmL = gm0 & 2047;
        ushort4 o;
        o.x = f2bf(acc[mi][ni][0] + bias);
        o.y = f2bf(acc[mi][ni][1] + bias);
        o.z = f2bf(acc[mi][ni][2] + bias);
        o.w = f2bf(acc[mi][ni][3] + bias);
        *(ushort4*)((ushort*)C2 + (long long)b2 * (512 * 2048) +
                    (long long)(gn - 1024) * 2048 + gmL) = o;
      }
    }
    return;
  }

  // Transposing epilogue: per wave a 16x64 f32 tile (stride 68, 4352B) in the
  // staging LDS (4 waves * 4352 = 17408B <= 32768B). 4 passes (one per mi).
  __syncthreads();  // all waves done reading staging LDS
  float* shf = (float*)&sh[0][0];
  const int wbase = w * 1088;  // floats

#pragma unroll
  for (int mi = 0; mi < 4; mi++) {
    // -- write phase: 16 scalar ds_writes (2-way bank alias max: free)
#pragma unroll
    for (int ni = 0; ni < 4; ni++) {
#pragma unroll
      for (int r = 0; r < 4; r++) {
        float v = acc[mi][ni][r];
        if (MODE == EP_QKV) v += biasv[ni];
        if (MODE == EP_SCALE) v *= scale;
        shf[wbase + (quad * 4 + r) * 68 + ni * 16 + l15] = v;
      }
    }
    asm volatile("s_waitcnt lgkmcnt(0)" ::: "memory");
    __builtin_amdgcn_sched_barrier(0);

    const int gmb = m0 + wr + mi * 16;
    if (MODE == EP_FINAL) {
      // fp32 out: 4 sub-iters of (4 rows x 16 lanes x float4) = 256B segments
#pragma unroll
      for (int j = 0; j < 4; j++) {
        const int rr = j * 4 + (lane >> 4);
        const int c0 = (lane & 15) * 4;
        float4 f = *(const float4*)&shf[wbase + rr * 68 + c0];
        const int gm = gmb + rr;
        const int gn = n0 + wc + c0;
        float4 x = *(const float4*)(aux + (long long)b * sAux +
                                    (long long)gm * N + gn);
        f.x += x.x; f.y += x.y; f.z += x.z; f.w += x.w;
        *(float4*)((float*)C + (long long)b * sC + (long long)gm * ldc + gn) = f;
      }
    } else {
      // bf16 out: 2 sub-iters of (8 rows x 8 lanes x ushort8) = 128B segments
#pragma unroll
      for (int j = 0; j < 2; j++) {
        const int rr = j * 8 + (lane >> 3);
        const int c0 = (lane & 7) * 8;
        float4 f0 = *(const float4*)&shf[wbase + rr * 68 + c0];
        float4 f1 = *(const float4*)&shf[wbase + rr * 68 + c0 + 4];
        const int gm = gmb + rr;
        const int gn = n0 + wc + c0;
        float vv[8] = {f0.x, f0.y, f0.z, f0.w, f1.x, f1.y, f1.z, f1.w};
        ushort* base;
        long long off;
        if (MODE == EP_QKV) {
          if (reg == 0) { base = (ushort*)C;  off = (long long)gm * ldc + gn; }
          else          { base = (ushort*)C3; off = (long long)gm * ldc + (gn - 512); }
        } else {
          base = (ushort*)C;
          off = (long long)b * sC + (long long)gm * ldc + gn;
        }
        if (MODE == EP_ACC && ACCUM) {
          ushortx8 old = *(const ushortx8*)(base + off);
#pragma unroll
          for (int e = 0; e < 8; e++) vv[e] += bf2f(old[e]);
        }
        ushortx8 o;
#pragma unroll
        for (int e = 0; e < 8; e++) o[e] = f2bf(vv[e]);
        *(ushortx8*)(base + off) = o;
      }
    }
  }
}

// ---------------- row softmax over 2048 bf16, in place ----------------
// One wave per row: 32 elems/lane, pure shfl reduce. No LDS, no barriers.
// 4 rows per 256-thread block; grid = 16384/4 = 4096.
__global__ __launch_bounds__(256) void softmax_rows(ushort* __restrict__ S) {
  const int w = threadIdx.x >> 6;
  const int lane = threadIdx.x & 63;
  const long long row = (long long)blockIdx.x * 4 + w;
  ushort* p = S + (row << 11);

  uint4 raw[4];
  float v[32];
#pragma unroll
  for (int c = 0; c < 4; c++) {
    raw[c] = *(const uint4*)(p + (c << 9) + (lane << 3));
    const ushort* rs = (const ushort*)&raw[c];
#pragma unroll
    for (int i = 0; i < 8; i++) v[c * 8 + i] = bf2f(rs[i]);
  }

  float mx = v[0];
#pragma unroll
  for (int i = 1; i < 32; i++) mx = fmaxf(mx, v[i]);
#pragma unroll
  for (int off = 32; off; off >>= 1) mx = fmaxf(mx, __shfl_xor(mx, off, 64));

  float s = 0.f;
#pragma unroll
  for (int i = 0; i < 32; i++) {
    v[i] = __expf(v[i] - mx);
    s += v[i];
  }
#pragma unroll
  for (int off = 32; off; off >>= 1) s += __shfl_xor(s, off, 64);
  const float inv = 1.0f / s;

#pragma unroll
  for (int c = 0; c < 4; c++) {
    ushort o[8];
#pragma unroll
    for (int i = 0; i < 8; i++) o[i] = f2bf(v[c * 8 + i] * inv);
    *(uint4*)(p + (c << 9) + (lane << 3)) = *(const uint4*)o;
  }
}

// ---------------- orchestration ----------------
extern "C" void kernel_launch(void* const* d_in, const int* in_sizes, int n_in,
                              void* d_out, int out_size, void* d_ws, size_t ws_size,
                              hipStream_t stream) {
  const float* Itime = (const float*)d_in[0];
  const float* Ispace = (const float*)d_in[1];
  const float* x0 = (const float*)d_in[2];
  const float* Wq = (const float*)d_in[3];
  const float* bq = (const float*)d_in[4];
  const float* Wk = (const float*)d_in[5];
  const float* bk = (const float*)d_in[6];
  const float* Wv = (const float*)d_in[7];
  const float* bv = (const float*)d_in[8];
  float* out = (float*)d_out;

  const long long SZX = 8388608;        // 8*2048*512
  const long long SZWP = 4LL * 1536 * 512;
  const long long SZS = 33554432;       // 8*2048*2048

  ushort* p = (ushort*)d_ws;
  ushort* Tb = p;   p += SZX;    // Itime bf16
  ushort* Sb = p;   p += SZX;    // Ispace bf16
  ushort* Wp = p;   p += SZWP;   // packed [4][1536][512] (Q,K,V rows)
  ushort* Qb = p;   p += SZX;    // Q proj [16384][512]
  ushort* Kb = p;   p += SZX;    // K proj [16384][512]
  ushort* Vt = p;   p += SZX;    // V^T [8][512][2048]
  ushort* Abf = p;  p += SZX;    // FTT + FTS
  ushort* Cbf = p;  p += SZX;    // FSS + FST
  ushort* Sc = p;   p += SZS;    // scores / probs (bf16)
  float* Bp = (float*)p;         // packed biases [4][1536] fp32 (24 KB)
  // total ws use ≈ 190.9 MB

  const dim3 blk(256);
  cvt_f32_bf16<<<dim3(8192), blk, 0, stream>>>(Itime, Tb, SZX);
  cvt_f32_bf16<<<dim3(8192), blk, 0, stream>>>(Ispace, Sb, SZX);
  pack_w<<<dim3(3072), blk, 0, stream>>>(Wq, Wk, Wv, Wp);
  pack_b<<<dim3(24), blk, 0, stream>>>(bq, bk, bv, Bp);

  const float scale = 0.04419417382415922f;  // 1/sqrt(512)

  auto attn = [&](const ushort* qs, const ushort* kvs, int pi,
                  ushort* dest, bool accum) {
    const ushort* Wqi = Wp + (long long)pi * 1536 * 512;
    const float* Bqi = Bp + pi * 1536;
    // Fused Q+K+V projection: [16384,1536]; region (Q/K/V) block-uniform.
    // Q -> Qb, K -> Kb, V -> Vt (transposed per batch).
    gemm_bt<EP_QKV, false><<<dim3(12, 128, 1), blk, 0, stream>>>(
        qs, kvs, Wqi, Qb, Vt, Kb, Bqi, 16384, 1536, 512, 512, 512, 512,
        0, 0, 0, 0, 0.f);
    // scores: S = scale * Q K^T (per batch 2048x2048)
    gemm_bt<EP_SCALE, false><<<dim3(16, 16, 8), blk, 0, stream>>>(
        Qb, Qb, Kb, Sc, nullptr, nullptr, nullptr, 2048, 2048, 512, 512, 512,
        2048, 1048576, 1048576, 4194304, 0, scale);
    softmax_rows<<<dim3(4096), blk, 0, stream>>>(Sc);
    // O (+)= P V : per batch M=2048, N=512, K=2048; B operand = Vt rows
    if (accum)
      gemm_bt<EP_ACC, true><<<dim3(4, 16, 8), blk, 0, stream>>>(
          Sc, Sc, Vt, dest, nullptr, nullptr, nullptr, 2048, 512, 2048, 2048,
          2048, 512, 4194304, 1048576, 1048576, 0, 0.f);
    else
      gemm_bt<EP_ACC, false><<<dim3(4, 16, 8), blk, 0, stream>>>(
          Sc, Sc, Vt, dest, nullptr, nullptr, nullptr, 2048, 512, 2048, 2048,
          2048, 512, 4194304, 1048576, 1048576, 0, 0.f);
  };

  attn(Tb, Tb, 0, Abf, false);   // FTT
  attn(Tb, Sb, 2, Abf, true);    // + FTS
  attn(Sb, Sb, 1, Cbf, false);   // FSS
  attn(Sb, Tb, 3, Cbf, true);    // + FST

  // out = Abf . Cbf^T + x_origin (fp32)
  gemm_bt<EP_FINAL, false><<<dim3(16, 16, 8), blk, 0, stream>>>(
      Abf, Abf, Cbf, out, nullptr, nullptr, x0, 2048, 2048, 512, 512, 512,
      2048, 1048576, 1048576, 4194304, 4194304, 0.f);
}